// Round 1
// baseline (16142.868 us; speedup 1.0000x reference)
//
#include <hip/hip_runtime.h>

#define N_USERS 200000
#define N_ITEMS 400000
#define N_NODES 600000   // N_USERS + N_ITEMS
#define EMB_DIM 128
#define N_EDGES 3000000

// element counts
#define TOT4  (N_NODES * (EMB_DIM / 4))   // 19,200,000 float4
#define NU4   (N_USERS * (EMB_DIM / 4))   //  6,400,000 float4

// ---------------------------------------------------------------------------
// init: cur = concat(emb_user, emb_item); acc = cur; next = 0
// ---------------------------------------------------------------------------
__global__ void k_init(const float4* __restrict__ eu, const float4* __restrict__ ei,
                       float4* __restrict__ cur, float4* __restrict__ acc,
                       float4* __restrict__ nxt) {
    for (int i = blockIdx.x * blockDim.x + threadIdx.x; i < TOT4;
         i += gridDim.x * blockDim.x) {
        float4 v = (i < NU4) ? eu[i] : ei[i - NU4];
        cur[i] = v;
        acc[i] = v;
        nxt[i] = make_float4(0.f, 0.f, 0.f, 0.f);
    }
}

// ---------------------------------------------------------------------------
// COO SpMM scatter: y[row[e]] += val[e] * x[col[e]]
// 32 lanes per edge, float4 per lane (covers 128 dims). 8 edges per 256-block.
// ---------------------------------------------------------------------------
__global__ void k_spmm(const int* __restrict__ row, const int* __restrict__ col,
                       const float* __restrict__ val, const float4* __restrict__ x,
                       float* __restrict__ y) {
    const int lane  = threadIdx.x & 31;   // dim group: dims [lane*4, lane*4+4)
    const int eslot = threadIdx.x >> 5;   // 0..7
    const int epb   = blockDim.x >> 5;    // edges per block = 8
    for (int e = blockIdx.x * epb + eslot; e < N_EDGES; e += gridDim.x * epb) {
        const int   r = row[e];
        const int   c = col[e];
        const float v = val[e];
        float4 xv = x[c * (EMB_DIM / 4) + lane];
        float* yp = y + (size_t)r * EMB_DIM + lane * 4;
        atomicAdd(yp + 0, v * xv.x);
        atomicAdd(yp + 1, v * xv.y);
        atomicAdd(yp + 2, v * xv.z);
        atomicAdd(yp + 3, v * xv.w);
    }
}

// ---------------------------------------------------------------------------
// acc += nxt; zbuf = 0   (zbuf becomes the next layer's scatter target)
// ---------------------------------------------------------------------------
__global__ void k_add_zero(float4* __restrict__ acc, const float4* __restrict__ nxt,
                           float4* __restrict__ zbuf) {
    for (int i = blockIdx.x * blockDim.x + threadIdx.x; i < TOT4;
         i += gridDim.x * blockDim.x) {
        float4 a = acc[i], b = nxt[i];
        a.x += b.x; a.y += b.y; a.z += b.z; a.w += b.w;
        acc[i] = a;
        zbuf[i] = make_float4(0.f, 0.f, 0.f, 0.f);
    }
}

// ---------------------------------------------------------------------------
// acc = (acc + nxt) * 0.25   (final layer + mean over 4-layer stack)
// ---------------------------------------------------------------------------
__global__ void k_add_scale(float4* __restrict__ acc, const float4* __restrict__ nxt) {
    for (int i = blockIdx.x * blockDim.x + threadIdx.x; i < TOT4;
         i += gridDim.x * blockDim.x) {
        float4 a = acc[i], b = nxt[i];
        a.x = (a.x + b.x) * 0.25f;
        a.y = (a.y + b.y) * 0.25f;
        a.z = (a.z + b.z) * 0.25f;
        a.w = (a.w + b.w) * 0.25f;
        acc[i] = a;
    }
}

extern "C" void kernel_launch(void* const* d_in, const int* in_sizes, int n_in,
                              void* d_out, int out_size, void* d_ws, size_t ws_size,
                              hipStream_t stream) {
    const float* eu   = (const float*)d_in[0];
    const float* ei   = (const float*)d_in[1];
    const int*   erow = (const int*)d_in[2];
    const int*   ecol = (const int*)d_in[3];
    const float* eval = (const float*)d_in[4];

    float* acc = (float*)d_out;
    float* ws0 = (float*)d_ws;                       // cur / ping
    float* ws1 = ws0 + (size_t)N_NODES * EMB_DIM;    // next / pong

    const int EW_BLOCK = 256;
    const int EW_GRID  = (TOT4 + EW_BLOCK - 1) / EW_BLOCK;   // 75,000 blocks

    const int SP_BLOCK = 256;                                 // 8 edges/block
    const int SP_GRID  = (N_EDGES + 7) / 8;                   // 375,000 blocks

    // acc = cur = concat; ws1 zeroed for layer-1 scatter
    k_init<<<EW_GRID, EW_BLOCK, 0, stream>>>(
        (const float4*)eu, (const float4*)ei,
        (float4*)ws0, (float4*)acc, (float4*)ws1);

    // layer 1: ws1 = SpMM(ws0); acc += ws1; zero ws0
    k_spmm<<<SP_GRID, SP_BLOCK, 0, stream>>>(erow, ecol, eval, (const float4*)ws0, ws1);
    k_add_zero<<<EW_GRID, EW_BLOCK, 0, stream>>>((float4*)acc, (const float4*)ws1, (float4*)ws0);

    // layer 2: ws0 = SpMM(ws1); acc += ws0; zero ws1
    k_spmm<<<SP_GRID, SP_BLOCK, 0, stream>>>(erow, ecol, eval, (const float4*)ws1, ws0);
    k_add_zero<<<EW_GRID, EW_BLOCK, 0, stream>>>((float4*)acc, (const float4*)ws0, (float4*)ws1);

    // layer 3: ws1 = SpMM(ws0); acc = (acc + ws1) * 0.25
    k_spmm<<<SP_GRID, SP_BLOCK, 0, stream>>>(erow, ecol, eval, (const float4*)ws0, ws1);
    k_add_scale<<<EW_GRID, EW_BLOCK, 0, stream>>>((float4*)acc, (const float4*)ws1);
}